// Round 10
// baseline (325.365 us; speedup 1.0000x reference)
//
#include <hip/hip_runtime.h>
#include <hip/hip_bf16.h>

// DirectionalPropagation1D fused v10: B=16, C=64, H=256, W=256, N=4096 seqs.
// Theory: R2-R9 all bound by DRAM granule efficiency (64B runs @1KB stride).
// v10 doubles the run length: 32-w superchunks, feat loads = 128B contiguous
// runs into 2x64KB LDS ping-pong; out written DIRECTLY by the rec wave as
// f32x4 (4 steps reg-buffered), relying on L2 dirty-line combining.
// Rec wave = v9 verbatim math (permuted-Ws register-state recurrence).
// Waves 1-2 = feat stagers (software-pipelined 2-group ring), wave 3 = gates.
// 9 lgkm-only barriers; no cross-buffer reads before the barrier (v9's
// latent boundary-prefetch race removed).

typedef __attribute__((ext_vector_type(8))) short short8;
typedef __attribute__((ext_vector_type(4))) float f32x4;

union FragU { unsigned int u[4]; short8 v; };

__device__ __forceinline__ unsigned int pk2(float a, float b) {
    unsigned short lo = __bfloat16_as_ushort(__float2bfloat16(a));
    unsigned short hi = __bfloat16_as_ushort(__float2bfloat16(b));
    return (unsigned int)lo | ((unsigned int)hi << 16);
}

// feat staging: per half, [w32][n16][c64] bf16.
// idx = w*1024 + ((n*64+c) ^ ((n&7)<<3) ^ ((w&7)<<3))  -- same pure function
// on stager-write and rec-read sides (rule 21). XOR terms stay below bit 10.
#define BAR() asm volatile("s_waitcnt lgkmcnt(0)\n\ts_barrier" ::: "memory")

__global__ __launch_bounds__(256, 1) void dp_v10_kernel(
    const float* __restrict__ feat, const float* __restrict__ conf,
    const float* __restrict__ Wi, const float* __restrict__ bi,
    const float* __restrict__ Ws, const float* __restrict__ bs,
    const float* __restrict__ bias, float* __restrict__ outp)
{
    __shared__ unsigned short fs[2][32768];  // 2 x 64 KB feat bf16 superchunks
    __shared__ float gs[2][512];             // 2 x 2 KB gates [w32][n16]

    const int tid = threadIdx.x;
    const int lane = tid & 63;
    const int wid = tid >> 6;
    const int l15 = lane & 15, g4 = lane >> 4;
    const int nb = blockIdx.x;
    const int b = nb >> 4, h0 = (nb & 15) * 16;

    const float* fb = feat + (size_t)b * 64 * 65536 + (size_t)h0 * 256;

    if (wid == 0) {
        // ================= recurrence wave (v9 math verbatim) =============
        FragU Ai[4][2], As[4][2];
        #pragma unroll
        for (int t = 0; t < 4; ++t)
            #pragma unroll
            for (int h = 0; h < 2; ++h) {
                const float* si = Wi + (16 * t + l15) * 64 + 32 * h + g4 * 8;
                const float* ss = Ws + (16 * t + l15) * 64;
                #pragma unroll
                for (int d = 0; d < 4; ++d) {
                    Ai[t][h].u[d] = pk2(si[2 * d], si[2 * d + 1]);
                    const int c0 = 16 * (2 * h + (d >> 1)) + 4 * g4 + 2 * (d & 1);
                    As[t][h].u[d] = pk2(ss[c0], ss[c0 + 1]);
                }
            }
        f32x4 binit[4];
        #pragma unroll
        for (int t = 0; t < 4; ++t)
            #pragma unroll
            for (int r = 0; r < 4; ++r) {
                int o = 16 * t + 4 * g4 + r;
                binit[t][r] = bi[o] + bs[o] + bias[o];
            }

        FragU S0, S1;
        #pragma unroll
        for (int d = 0; d < 4; ++d) { S0.u[d] = 0u; S1.u[d] = 0u; }

        const int fo0 = (l15 * 64 + 8 * g4) ^ ((l15 & 7) << 3);
        const int fo1 = (l15 * 64 + 32 + 8 * g4) ^ ((l15 & 7) << 3);
        float* const obase = outp + (size_t)(b * 64 + 4 * g4) * 65536
                                  + (size_t)(h0 + l15) * 256;

        auto mstep = [&](const short8& F0, const short8& F1, float (&cur)[4][4]) {
            f32x4 a0 = binit[0], a1 = binit[1], a2 = binit[2], a3 = binit[3];
            a0 = __builtin_amdgcn_mfma_f32_16x16x32_bf16(Ai[0][0].v, F0, a0, 0, 0, 0);
            a1 = __builtin_amdgcn_mfma_f32_16x16x32_bf16(Ai[1][0].v, F0, a1, 0, 0, 0);
            a2 = __builtin_amdgcn_mfma_f32_16x16x32_bf16(Ai[2][0].v, F0, a2, 0, 0, 0);
            a3 = __builtin_amdgcn_mfma_f32_16x16x32_bf16(Ai[3][0].v, F0, a3, 0, 0, 0);
            a0 = __builtin_amdgcn_mfma_f32_16x16x32_bf16(Ai[0][1].v, F1, a0, 0, 0, 0);
            a1 = __builtin_amdgcn_mfma_f32_16x16x32_bf16(Ai[1][1].v, F1, a1, 0, 0, 0);
            a2 = __builtin_amdgcn_mfma_f32_16x16x32_bf16(Ai[2][1].v, F1, a2, 0, 0, 0);
            a3 = __builtin_amdgcn_mfma_f32_16x16x32_bf16(Ai[3][1].v, F1, a3, 0, 0, 0);
            a0 = __builtin_amdgcn_mfma_f32_16x16x32_bf16(As[0][0].v, S0.v, a0, 0, 0, 0);
            a1 = __builtin_amdgcn_mfma_f32_16x16x32_bf16(As[1][0].v, S0.v, a1, 0, 0, 0);
            a2 = __builtin_amdgcn_mfma_f32_16x16x32_bf16(As[2][0].v, S0.v, a2, 0, 0, 0);
            a3 = __builtin_amdgcn_mfma_f32_16x16x32_bf16(As[3][0].v, S0.v, a3, 0, 0, 0);
            a0 = __builtin_amdgcn_mfma_f32_16x16x32_bf16(As[0][1].v, S1.v, a0, 0, 0, 0);
            a1 = __builtin_amdgcn_mfma_f32_16x16x32_bf16(As[1][1].v, S1.v, a1, 0, 0, 0);
            a2 = __builtin_amdgcn_mfma_f32_16x16x32_bf16(As[2][1].v, S1.v, a2, 0, 0, 0);
            a3 = __builtin_amdgcn_mfma_f32_16x16x32_bf16(As[3][1].v, S1.v, a3, 0, 0, 0);
            #pragma unroll
            for (int r = 0; r < 4; ++r) {
                cur[0][r] = fmaxf(a0[r], 0.f);
                cur[1][r] = fmaxf(a1[r], 0.f);
                cur[2][r] = fmaxf(a2[r], 0.f);
                cur[3][r] = fmaxf(a3[r], 0.f);
            }
        };
        auto rebuild = [&](const float (&cur)[4][4], float gv) {
            float g0[4], g1[4], g2[4], g3[4];
            #pragma unroll
            for (int r = 0; r < 4; ++r) {
                g0[r] = cur[0][r] * gv; g1[r] = cur[1][r] * gv;
                g2[r] = cur[2][r] * gv; g3[r] = cur[3][r] * gv;
            }
            S0.u[0] = pk2(g0[0], g0[1]); S0.u[1] = pk2(g0[2], g0[3]);
            S0.u[2] = pk2(g1[0], g1[1]); S0.u[3] = pk2(g1[2], g1[3]);
            S1.u[0] = pk2(g2[0], g2[1]); S1.u[1] = pk2(g2[2], g2[3]);
            S1.u[2] = pk2(g3[0], g3[1]); S1.u[3] = pk2(g3[2], g3[3]);
        };

        float curQ[4][4][4];   // [t][r][w-quad], all statically indexed
        float pend[4][4];

        BAR();  // prologue: superchunk 0 staged

        #pragma unroll 1
        for (int sc = 0; sc < 8; ++sc) {
            const unsigned short* fsb = fs[sc & 1];
            const float* gsb = gs[sc & 1];
            // state carried across the barrier: gate of this sc's first step
            if (sc > 0) rebuild(pend, gsb[l15]);
            short8 Fn0 = *(const short8*)&fsb[fo0];
            short8 Fn1 = *(const short8*)&fsb[fo1];

            #pragma unroll 1
            for (int up = 0; up < 8; ++up) {
                #pragma unroll
                for (int q = 0; q < 4; ++q) {
                    const int u = 4 * up + q;
                    short8 F0 = Fn0, F1 = Fn1;
                    if (u < 31) {                 // same-buffer prefetch only
                        const int w1 = u + 1;
                        const int sw = (w1 & 7) << 3;
                        Fn0 = *(const short8*)&fsb[w1 * 1024 + (fo0 ^ sw)];
                        Fn1 = *(const short8*)&fsb[w1 * 1024 + (fo1 ^ sw)];
                    }
                    float cur[4][4];
                    mstep(F0, F1, cur);
                    #pragma unroll
                    for (int t = 0; t < 4; ++t)
                        #pragma unroll
                        for (int r = 0; r < 4; ++r) curQ[t][r][q] = cur[t][r];
                    if (u < 31) {
                        rebuild(cur, gsb[(u + 1) * 16 + l15]);
                    } else {                      // defer across the barrier
                        #pragma unroll
                        for (int t = 0; t < 4; ++t)
                            #pragma unroll
                            for (int r = 0; r < 4; ++r) pend[t][r] = cur[t][r];
                    }
                }
                // direct out stores: f32x4 per (t,r), 4 w per store
                const int w0g = sc * 32 + 4 * up;
                #pragma unroll
                for (int t = 0; t < 4; ++t)
                    #pragma unroll
                    for (int r = 0; r < 4; ++r) {
                        f32x4 v = { curQ[t][r][0], curQ[t][r][1],
                                    curQ[t][r][2], curQ[t][r][3] };
                        *(f32x4*)(obase + (size_t)(16 * t + r) * 65536 + w0g) = v;
                    }
            }
            BAR();
        }
    } else if (wid <= 2) {
        // ================= feat stagers (waves 1,2): 128 B runs ===========
        const int cb = (wid - 1) * 32;
        const int rr = lane >> 3, ll = lane & 7;   // 8 rows x 8 w-quads / inst

        auto ldg = [&](f32x4 (&ra)[2][4], int g, int w0) {
            #pragma unroll
            for (int nn = 0; nn < 2; ++nn)
                #pragma unroll
                for (int ci = 0; ci < 4; ++ci)
                    ra[nn][ci] = *(const f32x4*)(fb
                        + (size_t)(cb + 8 * ci + rr) * 65536
                        + (2 * g + nn) * 256 + w0 + 4 * ll);
        };
        auto wrg = [&](const f32x4 (&ra)[2][4], int g, unsigned short* half) {
            #pragma unroll
            for (int nn = 0; nn < 2; ++nn) {
                const int n = 2 * g + nn;
                #pragma unroll
                for (int ci = 0; ci < 4; ++ci) {
                    const int c = cb + 8 * ci + rr;
                    const int base = (n * 64 + c) ^ ((n & 7) << 3);
                    #pragma unroll
                    for (int e = 0; e < 4; ++e) {
                        const int w = 4 * ll + e;
                        half[w * 1024 + (base ^ ((w & 7) << 3))] =
                            __bfloat16_as_ushort(__float2bfloat16(ra[nn][ci][e]));
                    }
                }
            }
        };
        auto stage = [&](int hb, int w0) {
            unsigned short* half = fs[hb];
            f32x4 ra0[2][4], ra1[2][4];            // named -> static (rule 20)
            ldg(ra0, 0, w0);
            ldg(ra1, 1, w0);
            #pragma unroll 1
            for (int g2 = 0; g2 < 4; ++g2) {
                wrg(ra0, 2 * g2, half);
                if (g2 < 3) ldg(ra0, 2 * g2 + 2, w0);
                wrg(ra1, 2 * g2 + 1, half);
                if (g2 < 3) ldg(ra1, 2 * g2 + 3, w0);
            }
        };

        stage(0, 0);
        BAR();
        #pragma unroll 1
        for (int k = 0; k < 8; ++k) {
            if (k < 7) stage((k + 1) & 1, (k + 1) * 32);
            BAR();
        }
    } else {
        // ================= gate stager (wave 3) ===========================
        const int n = lane >> 2, qq = lane & 3;
        const float* const gbd = conf + ((size_t)(b * 256) + h0 + n) * 256;

        auto stage_g = [&](int hb, int w0) {
            f32x4 v0 = *(const f32x4*)(gbd + w0 + 4 * qq);
            f32x4 v1 = *(const f32x4*)(gbd + w0 + 16 + 4 * qq);
            float* gd = gs[hb];
            #pragma unroll
            for (int e = 0; e < 4; ++e) {
                gd[(4 * qq + e) * 16 + n] = v0[e];
                gd[(16 + 4 * qq + e) * 16 + n] = v1[e];
            }
        };

        stage_g(0, 0);
        BAR();
        #pragma unroll 1
        for (int k = 0; k < 8; ++k) {
            if (k < 7) stage_g((k + 1) & 1, (k + 1) * 32);
            BAR();
        }
    }
}

extern "C" void kernel_launch(void* const* d_in, const int* in_sizes, int n_in,
                              void* d_out, int out_size, void* d_ws, size_t ws_size,
                              hipStream_t stream) {
    const float* feat = (const float*)d_in[0];
    const float* conf = (const float*)d_in[1];
    const float* Wi   = (const float*)d_in[2];
    const float* bi   = (const float*)d_in[3];
    const float* Ws   = (const float*)d_in[4];
    const float* bs   = (const float*)d_in[5];
    const float* bias = (const float*)d_in[6];
    float* out = (float*)d_out;
    (void)d_ws; (void)ws_size; (void)in_sizes; (void)n_in; (void)out_size;

    dp_v10_kernel<<<256, 256, 0, stream>>>(feat, conf, Wi, bi, Ws, bs, bias, out);
}